// Round 3
// baseline (488.003 us; speedup 1.0000x reference)
//
#include <hip/hip_runtime.h>
#include <math.h>

#define SCALE 0.125f

typedef __bf16 bf16;
typedef __bf16 bf16x8 __attribute__((ext_vector_type(8)));
typedef float f32x4 __attribute__((ext_vector_type(4)));

// workspace byte offsets
#define WS_XB   0u            // x bf16:   4096*512*2          = 4 MB
#define WS_WB   4194304u      // Wq,Wk,Wv,Wo bf16: 4*512*512*2 = 2 MB
#define WS_Q    6291456u      // q  [b][h][n][d] bf16          = 4 MB
#define WS_K    10485760u     // k  [b][h][n][d] bf16          = 4 MB
#define WS_VT   14680064u     // vT [b][h][d][n] bf16          = 4 MB
#define WS_AT   18874368u     // attn out [b][n][h*64+d] bf16  = 4 MB

// ---------------- Kernel A: fp32 -> bf16 pack ----------------
__global__ __launch_bounds__(256) void convert_kernel(
    const float* __restrict__ x, const float* __restrict__ wq,
    const float* __restrict__ wk, const float* __restrict__ wv,
    const float* __restrict__ wo, bf16* __restrict__ xb, bf16* __restrict__ wb) {
  int i = blockIdx.x * 256 + threadIdx.x;  // float4 index; total 786432
  const float4* src; bf16* dst; int off;
  if (i < 524288) { src = (const float4*)x; dst = xb; off = i; }
  else {
    int j = i - 524288;
    int wsel = j >> 16; off = j & 65535;
    const float* wl = wsel == 0 ? wq : wsel == 1 ? wk : wsel == 2 ? wv : wo;
    src = (const float4*)wl; dst = wb + (wsel << 18);
  }
  float4 v = src[off];
  union { bf16 h[4]; uint2 u; } tmp;
  tmp.h[0] = (bf16)v.x; tmp.h[1] = (bf16)v.y;
  tmp.h[2] = (bf16)v.z; tmp.h[3] = (bf16)v.w;
  ((uint2*)dst)[off] = tmp.u;
}

// ---------------- Kernel B: QKV projection GEMM (128x64 tiles) ----------------
__global__ __launch_bounds__(256) void qkv_gemm(
    const bf16* __restrict__ xb, const bf16* __restrict__ wb,
    const float* __restrict__ bq, const float* __restrict__ bk,
    const float* __restrict__ bv, bf16* __restrict__ qws,
    bf16* __restrict__ kws, bf16* __restrict__ vtws) {
  __shared__ bf16 Al[128 * 40];
  __shared__ bf16 Bl[64 * 40];
  int t = threadIdx.x;
  int m0 = (blockIdx.x & 31) << 7;   // 32 M-tiles of 128
  int n0 = (blockIdx.x >> 5) << 6;   // 24 N-tiles of 64
  int lane = t & 63, w = t >> 6;
  int quad = lane >> 4, col = lane & 15;
  int mblk = (w & 1) * 64, nblk = (w >> 1) * 32;  // wave: 64x32
  f32x4 acc[4][2] = {};
  for (int k0 = 0; k0 < 512; k0 += 32) {
    __syncthreads();
    for (int pass = 0; pass < 2; ++pass) {
      int c = t + (pass << 8);
      int row = c >> 2, part = c & 3;
      *(uint4*)&Al[row * 40 + part * 8] =
          *(const uint4*)&xb[(m0 + row) * 512 + k0 + part * 8];
    }
    {
      int row = t >> 2, part = t & 3;
      *(uint4*)&Bl[row * 40 + part * 8] =
          *(const uint4*)&wb[(n0 + row) * 512 + k0 + part * 8];
    }
    __syncthreads();
    bf16x8 af[4], bfv[2];
    for (int i = 0; i < 4; i++)
      af[i] = *(const bf16x8*)&Al[(mblk + i * 16 + col) * 40 + quad * 8];
    for (int i = 0; i < 2; i++)
      bfv[i] = *(const bf16x8*)&Bl[(nblk + i * 16 + col) * 40 + quad * 8];
    for (int mi = 0; mi < 4; mi++)
      for (int ni = 0; ni < 2; ni++)
        acc[mi][ni] = __builtin_amdgcn_mfma_f32_16x16x32_bf16(
            af[mi], bfv[ni], acc[mi][ni], 0, 0, 0);
  }
  for (int mi = 0; mi < 4; mi++)
    for (int ni = 0; ni < 2; ni++) {
      int n = n0 + nblk + ni * 16 + col;
      int wid = n >> 9, feat = n & 511;
      float bias = wid == 0 ? bq[feat] : wid == 1 ? bk[feat] : bv[feat];
      int h = feat >> 6, d = feat & 63;
      int mbase = m0 + mblk + mi * 16 + quad * 4;
      int bidx = mbase >> 11, seq0 = mbase & 2047;
      if (wid == 2) {
        union { bf16 h4[4]; ushort4 u4; } pk;
        for (int r = 0; r < 4; r++) pk.h4[r] = (bf16)(acc[mi][ni][r] + bias);
        *(ushort4*)&vtws[(size_t)((((bidx << 3) + h) << 6) + d) * 2048 + seq0] = pk.u4;
      } else {
        bf16* dst = wid == 0 ? qws : kws;
        for (int r = 0; r < 4; r++)
          dst[(size_t)((((bidx << 3) + h) << 11) + seq0 + r) * 64 + d] =
              (bf16)(acc[mi][ni][r] + bias);
      }
    }
}

// ---------------- Kernel C: flash attention, ONE WAVE per block ----------------
// 16 Q rows per wave; no __syncthreads anywhere; K/V/bias direct global->reg;
// K prefetch distance 1, bias distance 2 via unroll-2 register rotation.
__global__ __launch_bounds__(64, 2) void attn_kernel(
    const bf16* __restrict__ qws, const bf16* __restrict__ kws,
    const bf16* __restrict__ vtws, const float* __restrict__ gbias,
    bf16* __restrict__ attn) {
  __shared__ bf16 Pl[16 * 72];
  int lane = threadIdx.x;
  int quad = lane >> 4, col = lane & 15;
  int bid = blockIdx.x;            // 2048 = 16 bh * 128 qtiles
  int bh = bid >> 7, qt = bid & 127;
  int q0 = qt << 4;
  const bf16* qbase = qws + (size_t)bh * 2048 * 64;
  const bf16* kbase = kws + (size_t)bh * 2048 * 64;
  const bf16* vbase = vtws + (size_t)bh * 64 * 2048;
  const float* bb = gbias + ((size_t)bh * 2048 + q0) * 2048;

  // Q fragment (A-operand): rows q0..q0+15
  bf16x8 aq[2];
#pragma unroll
  for (int ks = 0; ks < 2; ++ks)
    aq[ks] = *(const bf16x8*)&qbase[(q0 + col) * 64 + ks * 32 + quad * 8];

  f32x4 o[4] = {};
  float mrow[4], lrow[4];
#pragma unroll
  for (int r = 0; r < 4; r++) { mrow[r] = -INFINITY; lrow[r] = 0.f; }

  // rotated prefetch buffers
  bf16x8 k2[2][8];   // K fragments (B-operand), distance 1
  float bc[2][16];   // bias, distance 2
#pragma unroll
  for (int nt = 0; nt < 4; ++nt)
#pragma unroll
    for (int ks = 0; ks < 2; ++ks)
      k2[0][nt * 2 + ks] =
          *(const bf16x8*)&kbase[(nt * 16 + col) * 64 + ks * 32 + quad * 8];
#pragma unroll
  for (int r = 0; r < 4; r++)
#pragma unroll
    for (int nt = 0; nt < 4; nt++) {
      const float* brow = bb + (size_t)(quad * 4 + r) * 2048;
      bc[0][r * 4 + nt] = brow[nt * 16 + col];
      bc[1][r * 4 + nt] = brow[64 + nt * 16 + col];
    }

  for (int kt = 0; kt < 32; kt += 2) {
#pragma unroll
    for (int u = 0; u < 2; ++u) {
      const int cur = u, nxt = 1 - u;
      int kt_ = kt + u;
      int s0 = kt_ << 6;

      // V fragments for CURRENT tile (needed after softmax -> latency covered)
      bf16x8 vr[8];
#pragma unroll
      for (int ks = 0; ks < 2; ++ks)
#pragma unroll
        for (int dt = 0; dt < 4; ++dt)
          vr[ks * 4 + dt] = *(const bf16x8*)&vbase[
              (size_t)(dt * 16 + col) * 2048 + s0 + ks * 32 + quad * 8];

      // K fragments for NEXT tile
      if (kt_ < 31) {
        int s1 = s0 + 64;
#pragma unroll
        for (int nt = 0; nt < 4; ++nt)
#pragma unroll
          for (int ks = 0; ks < 2; ++ks)
            k2[nxt][nt * 2 + ks] = *(const bf16x8*)&kbase[
                (s1 + nt * 16 + col) * 64 + ks * 32 + quad * 8];
      }

      // S = Q K^T
      f32x4 s[4];
#pragma unroll
      for (int nt = 0; nt < 4; ++nt) {
        f32x4 a = {};
        a = __builtin_amdgcn_mfma_f32_16x16x32_bf16(aq[0], k2[cur][nt * 2], a, 0, 0, 0);
        a = __builtin_amdgcn_mfma_f32_16x16x32_bf16(aq[1], k2[cur][nt * 2 + 1], a, 0, 0, 0);
        s[nt] = a;
      }

      // online softmax (C-layout), bias from regs
#pragma unroll
      for (int r = 0; r < 4; r++) {
        float sv[4];
        float mx = -INFINITY;
#pragma unroll
        for (int nt = 0; nt < 4; nt++) {
          sv[nt] = s[nt][r] * SCALE + bc[cur][r * 4 + nt];
          mx = fmaxf(mx, sv[nt]);
        }
#pragma unroll
        for (int d = 1; d < 16; d <<= 1) mx = fmaxf(mx, __shfl_xor(mx, d));
        float mnew = fmaxf(mrow[r], mx);
        float alpha = __expf(mrow[r] - mnew);
        float sum = 0.f;
#pragma unroll
        for (int nt = 0; nt < 4; nt++) {
          float e = __expf(sv[nt] - mnew);
          s[nt][r] = e; sum += e;
        }
#pragma unroll
        for (int d = 1; d < 16; d <<= 1) sum += __shfl_xor(sum, d);
        lrow[r] = lrow[r] * alpha + sum;
        mrow[r] = mnew;
#pragma unroll
        for (int dt = 0; dt < 4; ++dt) o[dt][r] *= alpha;
      }

      // bias for tile kt_+2 refills the buffer just consumed
      if (kt_ < 30) {
        int sb = (kt_ + 2) << 6;
#pragma unroll
        for (int r = 0; r < 4; r++) {
          const float* brow = bb + (size_t)(quad * 4 + r) * 2048 + sb;
#pragma unroll
          for (int nt = 0; nt < 4; nt++)
            bc[cur][r * 4 + nt] = brow[nt * 16 + col];
        }
      }

      // P: C-layout -> LDS -> A-operand (wave-private; lgkmcnt only)
#pragma unroll
      for (int nt = 0; nt < 4; nt++)
#pragma unroll
        for (int r = 0; r < 4; r++)
          Pl[(quad * 4 + r) * 72 + nt * 16 + col] = (bf16)s[nt][r];

#pragma unroll
      for (int ks = 0; ks < 2; ++ks) {
        bf16x8 ap = *(const bf16x8*)&Pl[col * 72 + ks * 32 + quad * 8];
#pragma unroll
        for (int dt = 0; dt < 4; ++dt)
          o[dt] = __builtin_amdgcn_mfma_f32_16x16x32_bf16(ap, vr[ks * 4 + dt], o[dt], 0, 0, 0);
      }
    }
  }

  // finalize: divide by l, store [b][seq][h*64+d] bf16
  bf16* obase = attn + (size_t)(bh >> 3) * 2048 * 512 + (bh & 7) * 64;
#pragma unroll
  for (int r = 0; r < 4; r++) {
    float inv = 1.f / lrow[r];
    int gq = q0 + quad * 4 + r;
#pragma unroll
    for (int dt = 0; dt < 4; ++dt)
      obase[(size_t)gq * 512 + dt * 16 + col] = (bf16)(o[dt][r] * inv);
  }
}

// ---------------- Kernel D: output projection (128x64 tiles) ----------------
__global__ __launch_bounds__(256) void out_gemm(
    const bf16* __restrict__ ab, const bf16* __restrict__ wob,
    const float* __restrict__ bo, float* __restrict__ out) {
  __shared__ bf16 Al[128 * 40];
  __shared__ bf16 Bl[64 * 40];
  int t = threadIdx.x;
  int m0 = (blockIdx.x & 31) << 7;   // 32 M-tiles
  int n0 = (blockIdx.x >> 5) << 6;   // 8 N-tiles
  int lane = t & 63, w = t >> 6;
  int quad = lane >> 4, col = lane & 15;
  int mblk = (w & 1) * 64, nblk = (w >> 1) * 32;
  f32x4 acc[4][2] = {};
  for (int k0 = 0; k0 < 512; k0 += 32) {
    __syncthreads();
    for (int pass = 0; pass < 2; ++pass) {
      int c = t + (pass << 8);
      int row = c >> 2, part = c & 3;
      *(uint4*)&Al[row * 40 + part * 8] =
          *(const uint4*)&ab[(m0 + row) * 512 + k0 + part * 8];
    }
    {
      int row = t >> 2, part = t & 3;
      *(uint4*)&Bl[row * 40 + part * 8] =
          *(const uint4*)&wob[(n0 + row) * 512 + k0 + part * 8];
    }
    __syncthreads();
    bf16x8 af[4], bfv[2];
    for (int i = 0; i < 4; i++)
      af[i] = *(const bf16x8*)&Al[(mblk + i * 16 + col) * 40 + quad * 8];
    for (int i = 0; i < 2; i++)
      bfv[i] = *(const bf16x8*)&Bl[(nblk + i * 16 + col) * 40 + quad * 8];
    for (int mi = 0; mi < 4; mi++)
      for (int ni = 0; ni < 2; ni++)
        acc[mi][ni] = __builtin_amdgcn_mfma_f32_16x16x32_bf16(
            af[mi], bfv[ni], acc[mi][ni], 0, 0, 0);
  }
  for (int mi = 0; mi < 4; mi++)
    for (int ni = 0; ni < 2; ni++)
      for (int r = 0; r < 4; r++) {
        int m = m0 + mblk + mi * 16 + quad * 4 + r;
        int n = n0 + nblk + ni * 16 + col;
        out[(size_t)m * 512 + n] = acc[mi][ni][r] + bo[n];
      }
}

extern "C" void kernel_launch(void* const* d_in, const int* in_sizes, int n_in,
                              void* d_out, int out_size, void* d_ws, size_t ws_size,
                              hipStream_t stream) {
  const float* x  = (const float*)d_in[0];
  const float* gb = (const float*)d_in[1];
  const float* Wq = (const float*)d_in[2];
  const float* bq = (const float*)d_in[3];
  const float* Wk = (const float*)d_in[4];
  const float* bk = (const float*)d_in[5];
  const float* Wv = (const float*)d_in[6];
  const float* bv = (const float*)d_in[7];
  const float* Wo = (const float*)d_in[8];
  const float* bo = (const float*)d_in[9];
  float* out = (float*)d_out;
  char* ws = (char*)d_ws;
  bf16* xb   = (bf16*)(ws + WS_XB);
  bf16* wb   = (bf16*)(ws + WS_WB);
  bf16* qws  = (bf16*)(ws + WS_Q);
  bf16* kws  = (bf16*)(ws + WS_K);
  bf16* vtws = (bf16*)(ws + WS_VT);
  bf16* at   = (bf16*)(ws + WS_AT);

  hipLaunchKernelGGL(convert_kernel, dim3(3072), dim3(256), 0, stream,
                     x, Wq, Wk, Wv, Wo, xb, wb);
  hipLaunchKernelGGL(qkv_gemm, dim3(768), dim3(256), 0, stream,
                     xb, wb, bq, bk, bv, qws, kws, vtws);
  hipLaunchKernelGGL(attn_kernel, dim3(2048), dim3(64), 0, stream,
                     qws, kws, vtws, gb, at);
  hipLaunchKernelGGL(out_gemm, dim3(256), dim3(256), 0, stream,
                     at, wb + 3 * 262144, bo, out);
}